// Round 4
// baseline (582.460 us; speedup 1.0000x reference)
//
#include <hip/hip_runtime.h>
#include <hip/hip_bf16.h>

// Eikonal3D: 64^3 grid, 128 Jacobi Godunov sweeps = 32 launches x 4 fused
// iterations (k=4 temporal blocking, 8^3 tiles, 16^3 halo regions).
// Thread = one (x,y) column of the region; 16 z-cells in registers; LDS
// holds one 16KB column plane per exchange. Monotone-convergence skip flags
// (27-neighborhood) preserve exact Jacobi-128 semantics.
// n_iter fixed at 128 by setup_inputs (host must know launch count).

#define NPTS (64 * 64 * 64)
#define BIGV 1000.0f
#define PADV 10000.0f   // BIG*10 pad value
#define NEV 4096
#define NBLK 512        // 8^3 blocks of 8^3 tiles
#define NPH 32          // 128 / 4

__device__ __forceinline__ float godunov_cell(float uc, float ax, float ay,
                                              float az, float f) {
    float lo = fminf(ax, ay), hi = fmaxf(ax, ay);
    float a1 = fminf(lo, az);
    float a3 = fmaxf(hi, az);
    float a2 = fminf(fmaxf(lo, az), hi);
    float x1 = a1 + f;
    float d12 = a1 - a2;
    float d2 = 2.0f * f * f - d12 * d12;
    float x2 = 0.5f * (a1 + a2 + sqrtf(fmaxf(d2, 0.0f)));
    float s = a1 + a2 + a3;
    float q = a1 * a1 + a2 * a2 + a3 * a3;
    float d3 = s * s - 3.0f * (q - f * f);
    float x3 = (s + sqrtf(fmaxf(d3, 0.0f))) * (1.0f / 3.0f);
    float unew = (x1 <= a2) ? x1 : ((x2 <= a3) ? x2 : x3);
    return fminf(uc, unew);
}

// one z-chunk (4 cells) Jacobi update; merge via per-element z-range mask
__device__ __forceinline__ float4 upd_chunk(float4 cc, float4 xm, float4 xp,
                                            float4 ym, float4 yp,
                                            float zprev, float znext, float4 f,
                                            int zb, int zlo, int zhi) {
    float n0 = godunov_cell(cc.x, fminf(xm.x, xp.x), fminf(ym.x, yp.x), fminf(zprev, cc.y), f.x);
    float n1 = godunov_cell(cc.y, fminf(xm.y, xp.y), fminf(ym.y, yp.y), fminf(cc.x, cc.z), f.y);
    float n2 = godunov_cell(cc.z, fminf(xm.z, xp.z), fminf(ym.z, yp.z), fminf(cc.y, cc.w), f.z);
    float n3 = godunov_cell(cc.w, fminf(xm.w, xp.w), fminf(ym.w, yp.w), fminf(cc.z, znext), f.w);
    float4 r;
    r.x = (zb + 0 >= zlo && zb + 0 <= zhi) ? n0 : cc.x;
    r.y = (zb + 1 >= zlo && zb + 1 <= zhi) ? n1 : cc.y;
    r.z = (zb + 2 >= zlo && zb + 2 <= zhi) ? n2 : cc.z;
    r.w = (zb + 3 >= zlo && zb + 3 <= zhi) ? n3 : cc.w;
    return r;
}

__global__ __launch_bounds__(256) void eik_init(const float* __restrict__ vp,
                                                const float* __restrict__ st,
                                                float* __restrict__ u,
                                                float* __restrict__ fh,
                                                int* __restrict__ flA) {
    int idx = blockIdx.x * blockDim.x + threadIdx.x;
    if (idx >= NPTS) return;
    float v = vp[idx];
    fh[idx] = 1.0f / v;

    if (idx < NBLK) flA[idx] = 1;   // everyone computes in phase 0

    int z = idx & 63;
    int y = (idx >> 6) & 63;
    int x = idx >> 12;

    float sx = st[0], sy = st[1], sz = st[2];
    int ix0 = min(max((int)floorf(sx), 0), 62);
    int iy0 = min(max((int)floorf(sy), 0), 62);
    int iz0 = min(max((int)floorf(sz), 0), 62);
    float xs = fminf(fmaxf(sx, 0.0f), 63.0f);
    float ys = fminf(fmaxf(sy, 0.0f), 63.0f);
    float zs = fminf(fmaxf(sz, 0.0f), 63.0f);

    float val = BIGV;
    if (x >= ix0 && x <= ix0 + 1 && y >= iy0 && y <= iy0 + 1 &&
        z >= iz0 && z <= iz0 + 1) {
        float dx = xs - (float)x;
        float dy = ys - (float)y;
        float dz = zs - (float)z;
        val = sqrtf(dx * dx + dy * dy + dz * dz) / v;
    }
    u[idx] = val;
}

__global__ __launch_bounds__(256) void eik_group(
    const float* __restrict__ src, float* __restrict__ dst,
    const float* __restrict__ fh,
    const int* __restrict__ fp, int* __restrict__ fn) {
    __shared__ float4 cols[4 * 256];   // [chunk][column] plane, 16 KB
    __shared__ int s_any;

    const int b = blockIdx.x;
    const int BX = b >> 6, BY = (b >> 3) & 7, BZ = b & 7;
    const int t = threadIdx.x;
    const int lx = t >> 4, ly = t & 15;            // thread = one (x,y) column
    const int gx = BX * 8 - 4 + lx, gy = BY * 8 - 4 + ly;
    const int oz = BZ * 8 - 4;
    const bool xyin = (gx >= 0) & (gx < 64) & (gy >= 0) & (gy < 64);
    const int rowbase = (xyin ? (gx * 64 + gy) * 64 : 0);
    const int moz = -oz, mzt = 63 - oz;
    const bool zin0 = (oz >= 0), zin3 = (oz + 12 <= 60);
    const bool writer = (lx >= 4) & (lx <= 11) & (ly >= 4) & (ly <= 11);

    // --- 27-neighborhood activity check ---
    if (t == 0) s_any = 0;
    __syncthreads();
    if (t < 27) {
        int dx = t / 9 - 1, dy = (t / 3) % 3 - 1, dz = t % 3 - 1;
        int nx = BX + dx, ny = BY + dy, nz = BZ + dz;
        if (nx >= 0 && nx < 8 && ny >= 0 && ny < 8 && nz >= 0 && nz < 8)
            if (fp[(nx << 6) | (ny << 3) | nz]) atomicOr(&s_any, 1);
    }
    __syncthreads();
    const int active = s_any;
    __syncthreads();

    if (!active) {
        // neighborhood quiet: output tile == input tile
        if (writer) {
            *(float4*)&dst[rowbase + oz + 4] = *(const float4*)&src[rowbase + oz + 4];
            *(float4*)&dst[rowbase + oz + 8] = *(const float4*)&src[rowbase + oz + 8];
        }
        if (t == 0) fn[b] = 0;
        return;
    }

    // fh column in registers (clamped addresses; only in-grid cells used)
    const int cgx = min(max(gx, 0), 63), cgy = min(max(gy, 0), 63);
    const int fb = (cgx * 64 + cgy) * 64;
    const float4 f0 = *(const float4*)&fh[fb + max(oz, 0)];
    const float4 f1 = *(const float4*)&fh[fb + oz + 4];
    const float4 f2 = *(const float4*)&fh[fb + oz + 8];
    const float4 f3 = *(const float4*)&fh[fb + min(oz + 12, 60)];
    const float4 PAD4 = make_float4(PADV, PADV, PADV, PADV);

    // own 16-z column (4 aligned chunks, each fully in or out of grid)
    float4 cc0 = (xyin && zin0) ? *(const float4*)&src[rowbase + oz]      : PAD4;
    float4 cc1 = xyin           ? *(const float4*)&src[rowbase + oz + 4]  : PAD4;
    float4 cc2 = xyin           ? *(const float4*)&src[rowbase + oz + 8]  : PAD4;
    float4 cc3 = (xyin && zin3) ? *(const float4*)&src[rowbase + oz + 12] : PAD4;
    const float4 st1 = cc1, st2 = cc2;   // stash tile chunks for change detect

    #pragma unroll
    for (int it = 0; it < 4; ++it) {
        cols[t] = cc0; cols[256 + t] = cc1;
        cols[512 + t] = cc2; cols[768 + t] = cc3;
        __syncthreads();
        const int s0 = it + 1, s1 = 14 - it;
        if ((lx >= s0) & (lx <= s1) & (ly >= s0) & (ly <= s1) & xyin) {
            const int zlo = max(s0, moz), zhi = min(s1, mzt);
            float4 xm0 = cols[t - 16], xp0 = cols[t + 16];
            float4 ym0 = cols[t - 1],  yp0 = cols[t + 1];
            float4 xm1 = cols[256 + t - 16], xp1 = cols[256 + t + 16];
            float4 ym1 = cols[256 + t - 1],  yp1 = cols[256 + t + 1];
            float4 xm2 = cols[512 + t - 16], xp2 = cols[512 + t + 16];
            float4 ym2 = cols[512 + t - 1],  yp2 = cols[512 + t + 1];
            float4 xm3 = cols[768 + t - 16], xp3 = cols[768 + t + 16];
            float4 ym3 = cols[768 + t - 1],  yp3 = cols[768 + t + 1];
            float4 n0 = upd_chunk(cc0, xm0, xp0, ym0, yp0, cc0.x, cc1.x, f0, 0,  zlo, zhi);
            float4 n1 = upd_chunk(cc1, xm1, xp1, ym1, yp1, cc0.w, cc2.x, f1, 4,  zlo, zhi);
            float4 n2 = upd_chunk(cc2, xm2, xp2, ym2, yp2, cc1.w, cc3.x, f2, 8,  zlo, zhi);
            float4 n3 = upd_chunk(cc3, xm3, xp3, ym3, yp3, cc2.w, cc3.w, f3, 12, zlo, zhi);
            cc0 = n0; cc1 = n1; cc2 = n2; cc3 = n3;
        }
        __syncthreads();
    }

    // write tile back + change detection
    if (t == 0) s_any = 0;
    __syncthreads();
    int chg = 0;
    if (writer) {
        *(float4*)&dst[rowbase + oz + 4] = cc1;
        *(float4*)&dst[rowbase + oz + 8] = cc2;
        chg = (cc1.x != st1.x) | (cc1.y != st1.y) | (cc1.z != st1.z) | (cc1.w != st1.w) |
              (cc2.x != st2.x) | (cc2.y != st2.y) | (cc2.z != st2.z) | (cc2.w != st2.w);
    }
    if (__any(chg) && (t & 63) == 0) atomicOr(&s_any, 1);
    __syncthreads();
    if (t == 0) fn[b] = s_any;
}

__global__ __launch_bounds__(1024) void eik_finalize(const float* __restrict__ u,
                                                     const float* __restrict__ evloc,
                                                     const float* __restrict__ evtime,
                                                     const float* __restrict__ phtime,
                                                     float* __restrict__ out) {
    __shared__ float red[16];
    int t = threadIdx.x;
    float acc = 0.0f;
    for (int i = t; i < NEV; i += 1024) {
        float x = evloc[3 * i + 0];
        float y = evloc[3 * i + 1];
        float z = evloc[3 * i + 2];
        int ix0 = min(max((int)floorf(x), 0), 62);
        int iy0 = min(max((int)floorf(y), 0), 62);
        int iz0 = min(max((int)floorf(z), 0), 62);
        float xs = fminf(fmaxf(x, 0.0f), 63.0f);
        float ys = fminf(fmaxf(y, 0.0f), 63.0f);
        float zs = fminf(fmaxf(z, 0.0f), 63.0f);
        float wx0 = xs - (float)ix0, wx1 = (float)(ix0 + 1) - xs;
        float wy0 = ys - (float)iy0, wy1 = (float)(iy0 + 1) - ys;
        float wz0 = zs - (float)iz0, wz1 = (float)(iz0 + 1) - zs;
        int base = ix0 * 4096 + iy0 * 64 + iz0;
        float tt = u[base]             * wx1 * wy1 * wz1 + u[base + 4096]          * wx0 * wy1 * wz1
                 + u[base + 64]        * wx1 * wy0 * wz1 + u[base + 4096 + 64]     * wx0 * wy0 * wz1
                 + u[base + 1]         * wx1 * wy1 * wz0 + u[base + 4096 + 1]      * wx0 * wy1 * wz0
                 + u[base + 64 + 1]    * wx1 * wy0 * wz0 + u[base + 4096 + 64 + 1] * wx0 * wy0 * wz0;
        float at = evtime[i] + tt;
        out[i] = at;
        float d = at - phtime[i];
        acc += d * d;
    }
    #pragma unroll
    for (int off = 32; off > 0; off >>= 1) acc += __shfl_down(acc, off);
    if ((t & 63) == 0) red[t >> 6] = acc;
    __syncthreads();
    if (t < 16) {
        float v = red[t];
        #pragma unroll
        for (int off = 8; off > 0; off >>= 1) v += __shfl_down(v, off);
        if (t == 0) out[NEV] = v * (1.0f / (float)NEV);
    }
}

extern "C" void kernel_launch(void* const* d_in, const int* in_sizes, int n_in,
                              void* d_out, int out_size, void* d_ws, size_t ws_size,
                              hipStream_t stream) {
    const float* vp     = (const float*)d_in[0];
    const float* stloc  = (const float*)d_in[1];
    const float* evloc  = (const float*)d_in[2];
    const float* evtime = (const float*)d_in[3];
    const float* phtime = (const float*)d_in[4];
    float* out = (float*)d_out;

    float* w  = (float*)d_ws;
    float* uA = w;                   // 64^3
    float* uB = w + NPTS;            // 64^3
    float* fh = w + 2 * NPTS;        // 64^3
    int* flA  = (int*)(w + 3 * NPTS);
    int* flB  = flA + NBLK;

    eik_init<<<NPTS / 256, 256, 0, stream>>>(vp, stloc, uA, fh, flA);

    for (int g = 0; g < NPH; ++g) {
        const float* s = (g & 1) ? uB : uA;
        float*       d = (g & 1) ? uA : uB;
        const int*  fp = (g & 1) ? flB : flA;
        int*        fn = (g & 1) ? flA : flB;
        eik_group<<<NBLK, 256, 0, stream>>>(s, d, fh, fp, fn);
    }
    // 32 phases (even) -> final field in uA

    eik_finalize<<<1, 1024, 0, stream>>>(uA, evloc, evtime, phtime, out);
}